// Round 3
// baseline (2266.032 us; speedup 1.0000x reference)
//
#include <hip/hip_runtime.h>
#include <math.h>

#define N_TOK 32768
#define K_CODES 4096
#define DIM 512
#define COMMIT 0.25f
#define NCAND 6

// ---------------------------------------------------------------------------
// Kernel 1: numpy-exact fp32 row sum of squares (pairwise algorithm).
// numpy pairwise_sum(512) = (pw128+pw128) + (pw128+pw128); each pw128 uses
// 8 accumulators r[j] += a[8t+j] then ((r0+r1)+(r2+r3))+((r4+r5)+(r6+r7)).
// 8 lanes per row (lane j = accumulator j); IEEE add commutativity makes the
// shfl_xor pairing bit-identical to numpy's ordering. Contraction OFF so the
// square is rounded before the add (numpy squares then sums).
// ---------------------------------------------------------------------------
__global__ __launch_bounds__(256) void rowsq_np_kernel(const float* __restrict__ a,
                                                       float* __restrict__ out,
                                                       int nrows) {
    #pragma clang fp contract(off)
    const int gw   = (blockIdx.x * 256 + threadIdx.x) >> 6;
    const int lane = threadIdx.x & 63;
    const int row  = gw * 8 + (lane >> 3);
    const int j    = lane & 7;
    if (row >= nrows) return;
    const float* p = a + (size_t)row * DIM;
    float blk[4];
    #pragma unroll
    for (int b = 0; b < 4; ++b) {
        const float* q = p + b * 128;
        float v = q[j];
        float r = v * v;
        for (int i = 8; i < 128; i += 8) { float u = q[i + j]; r += u * u; }
        float s1 = r  + __shfl_xor(r, 1);
        float s2 = s1 + __shfl_xor(s1, 2);
        float s3 = s2 + __shfl_xor(s2, 4);
        blk[b] = s3;
    }
    float res = (blk[0] + blk[1]) + (blk[2] + blk[3]);
    if (j == 0) out[row] = res;
}

// ---------------------------------------------------------------------------
// Kernel 2: fp32 GEMM pass over score s = w2[k] - 2*x.w; per-thread top-2,
// merged to top-6 candidates per token (covers the fp32 grid-tie set).
// ---------------------------------------------------------------------------
__global__ __launch_bounds__(256) void argmin_kernel(const float* __restrict__ x,
                                                     const float* __restrict__ w,
                                                     const float* __restrict__ w2,
                                                     int* __restrict__ cand) {
    __shared__ float As[32][128];   // [d][token]
    __shared__ float Bs[32][128];   // [d][code]
    __shared__ float W2s[128];

    const int tid = threadIdx.x;
    const int tx = tid & 15;        // code dim (8 codes each)
    const int ty = tid >> 4;        // token dim (8 tokens each)
    const int m0 = blockIdx.x * 128;

    float b1v[8], b2v[8];
    int   b1i[8], b2i[8];
    #pragma unroll
    for (int i = 0; i < 8; ++i) { b1v[i] = 3.4e38f; b2v[i] = 3.4e38f; b1i[i] = 0; b2i[i] = 0; }

    const int tok = tid >> 1;             // 0..127 (staging role)
    const int dof = (tid & 1) * 16;       // 0 or 16

    for (int nt = 0; nt < K_CODES / 128; ++nt) {
        const int n0 = nt * 128;

        __syncthreads();
        if (tid < 128) W2s[tid] = w2[n0 + tid];

        float acc[8][8];
        #pragma unroll
        for (int i = 0; i < 8; ++i)
            #pragma unroll
            for (int j = 0; j < 8; ++j) acc[i][j] = 0.f;

        for (int dk = 0; dk < DIM; dk += 32) {
            __syncthreads();
            {
                const float4* src = (const float4*)(x + (size_t)(m0 + tok) * DIM + dk + dof);
                #pragma unroll
                for (int j = 0; j < 4; ++j) {
                    float4 v = src[j];
                    int d = dof + j * 4;
                    As[d + 0][tok] = v.x;
                    As[d + 1][tok] = v.y;
                    As[d + 2][tok] = v.z;
                    As[d + 3][tok] = v.w;
                }
            }
            {
                const float4* src = (const float4*)(w + (size_t)(n0 + tok) * DIM + dk + dof);
                #pragma unroll
                for (int j = 0; j < 4; ++j) {
                    float4 v = src[j];
                    int d = dof + j * 4;
                    Bs[d + 0][tok] = v.x;
                    Bs[d + 1][tok] = v.y;
                    Bs[d + 2][tok] = v.z;
                    Bs[d + 3][tok] = v.w;
                }
            }
            __syncthreads();

            #pragma unroll
            for (int d = 0; d < 32; ++d) {
                const float4 a0 = *reinterpret_cast<const float4*>(&As[d][ty * 8]);
                const float4 a1 = *reinterpret_cast<const float4*>(&As[d][ty * 8 + 4]);
                const float4 c0 = *reinterpret_cast<const float4*>(&Bs[d][tx * 8]);
                const float4 c1 = *reinterpret_cast<const float4*>(&Bs[d][tx * 8 + 4]);
                const float av[8] = {a0.x, a0.y, a0.z, a0.w, a1.x, a1.y, a1.z, a1.w};
                const float bv[8] = {c0.x, c0.y, c0.z, c0.w, c1.x, c1.y, c1.z, c1.w};
                #pragma unroll
                for (int i = 0; i < 8; ++i)
                    #pragma unroll
                    for (int j = 0; j < 8; ++j)
                        acc[i][j] += av[i] * bv[j];
            }
        }

        #pragma unroll
        for (int i = 0; i < 8; ++i) {
            #pragma unroll
            for (int j = 0; j < 8; ++j) {
                int k = n0 + tx * 8 + j;
                float s = W2s[tx * 8 + j] - 2.0f * acc[i][j];
                if (s < b1v[i]) {
                    b2v[i] = b1v[i]; b2i[i] = b1i[i];
                    b1v[i] = s;      b1i[i] = k;
                } else if (s < b2v[i]) {
                    b2v[i] = s; b2i[i] = k;
                }
            }
        }
    }

    // merge 16 threads x top-2 = 32 entries per token -> top-6 candidates
    __syncthreads();
    float* fv = &As[0][0];          // 4096 floats (token*32 + tx*2 + slot)
    int*   fi = (int*)&Bs[0][0];    // 4096 ints
    #pragma unroll
    for (int i = 0; i < 8; ++i) {
        int e = (ty * 8 + i) * 32 + tx * 2;
        fv[e]     = b1v[i]; fi[e]     = b1i[i];
        fv[e + 1] = b2v[i]; fi[e + 1] = b2i[i];
    }
    __syncthreads();
    if (tid < 128) {
        float bv[NCAND]; int bi[NCAND];
        #pragma unroll
        for (int c = 0; c < NCAND; ++c) { bv[c] = 3.4e38f; bi[c] = 0x7fffffff; }
        for (int s = 0; s < 32; ++s) {
            float v = fv[tid * 32 + s];
            int   k = fi[tid * 32 + s];
            if (v < bv[NCAND - 1] || (v == bv[NCAND - 1] && k < bi[NCAND - 1])) {
                bv[NCAND - 1] = v; bi[NCAND - 1] = k;
                #pragma unroll
                for (int p = NCAND - 1; p > 0; --p) {
                    bool sw = (bv[p] < bv[p - 1]) || (bv[p] == bv[p - 1] && bi[p] < bi[p - 1]);
                    if (!sw) break;
                    float tv = bv[p]; bv[p] = bv[p - 1]; bv[p - 1] = tv;
                    int   tk = bi[p]; bi[p] = bi[p - 1]; bi[p - 1] = tk;
                }
            }
        }
        #pragma unroll
        for (int c = 0; c < NCAND; ++c) cand[(size_t)(m0 + tid) * NCAND + c] = bi[c];
    }
}

// ---------------------------------------------------------------------------
// Kernel 3: replicate the numpy fp32 pipeline on the candidates.
// d_k = fl32( fl32(x2_i + w2_k) - 2f * fl32(dot_fp64) ); argmin, ties->lowest k.
// One wave per token.
// ---------------------------------------------------------------------------
__global__ __launch_bounds__(256) void refine_kernel(const float* __restrict__ x,
                                                     const float* __restrict__ w,
                                                     const float* __restrict__ x2np,
                                                     const float* __restrict__ w2np,
                                                     const int* __restrict__ cand,
                                                     int* __restrict__ idx) {
    const int t    = blockIdx.x * 4 + (threadIdx.x >> 6);
    const int lane = threadIdx.x & 63;

    const float* xr = x + (size_t)t * DIM;
    float xv[8];
    #pragma unroll
    for (int j = 0; j < 8; ++j) xv[j] = xr[lane + 64 * j];
    const float x2 = x2np[t];

    float bd = 3.4e38f;
    int   bk = 0x7fffffff;
    for (int c = 0; c < NCAND; ++c) {
        int k = cand[(size_t)t * NCAND + c];
        const float* wr = w + (size_t)k * DIM;
        double m = 0.0;
        #pragma unroll
        for (int j = 0; j < 8; ++j)
            m = fma((double)xv[j], (double)wr[lane + 64 * j], m);
        #pragma unroll
        for (int off = 32; off >= 1; off >>= 1) m += __shfl_down(m, off);
        if (lane == 0) {
            #pragma clang fp contract(off)
            float m32 = (float)m;
            float T1  = x2 + w2np[k];
            float d   = T1 - 2.0f * m32;
            if (d < bd || (d == bd && k < bk)) { bd = d; bk = k; }
        }
    }
    if (lane == 0) idx[t] = bk;
}

// ---------------------------------------------------------------------------
// Kernel 4: gather + straight-through output + loss + counts.
// ---------------------------------------------------------------------------
__global__ __launch_bounds__(256) void gather_kernel(const float* __restrict__ x,
                                                     const float* __restrict__ w,
                                                     const int* __restrict__ idx,
                                                     float* __restrict__ out_q,
                                                     float* __restrict__ out_loss,
                                                     float* __restrict__ out_ind,
                                                     int* __restrict__ counts) {
    const int wave = threadIdx.x >> 6;
    const int lane = threadIdx.x & 63;
    const int token = blockIdx.x * 4 + wave;
    const int k = idx[token];

    const float4* xr = (const float4*)(x + (size_t)token * DIM);
    const float4* wr = (const float4*)(w + (size_t)k * DIM);
    float4*       qo = (float4*)(out_q + (size_t)token * DIM);

    float ss = 0.f;
    #pragma unroll
    for (int j = 0; j < 2; ++j) {
        int e = lane + j * 64;
        float4 xv = xr[e];
        float4 wv = wr[e];
        float4 d, o;
        d.x = wv.x - xv.x; o.x = xv.x + d.x;
        d.y = wv.y - xv.y; o.y = xv.y + d.y;
        d.z = wv.z - xv.z; o.z = xv.z + d.z;
        d.w = wv.w - xv.w; o.w = xv.w + d.w;
        ss += d.x * d.x + d.y * d.y + d.z * d.z + d.w * d.w;
        qo[e] = o;
    }
    #pragma unroll
    for (int off = 32; off >= 1; off >>= 1) ss += __shfl_down(ss, off);
    if (lane == 0) {
        float lm = ss * (1.0f / DIM);
        out_loss[token] = lm + COMMIT * lm;
        out_ind[token] = (float)k;
        atomicAdd(&counts[k], 1);
    }
}

// ---------------------------------------------------------------------------
// Kernel 5: perplexity from counts. Single 256-thread block, fp64 entropy.
// ---------------------------------------------------------------------------
__global__ __launch_bounds__(256) void perplex_kernel(const int* __restrict__ counts,
                                                      float* __restrict__ out2) {
    __shared__ double red[4];
    const int tid = threadIdx.x;
    const int lane = tid & 63;
    const int wid = tid >> 6;
    double s = 0.0;
    for (int t = tid; t < K_CODES; t += 256) {
        int c = counts[t];
        if (c) {
            double p = (double)c * (1.0 / N_TOK);
            s += p * log(p + 1e-10);
        }
    }
    #pragma unroll
    for (int off = 32; off >= 1; off >>= 1) s += __shfl_down(s, off);
    if (lane == 0) red[wid] = s;
    __syncthreads();
    if (tid == 0) {
        double t = red[0] + red[1] + red[2] + red[3];
        out2[0] = (float)exp(-t);
    }
}

// ---------------------------------------------------------------------------
extern "C" void kernel_launch(void* const* d_in, const int* in_sizes, int n_in,
                              void* d_out, int out_size, void* d_ws, size_t ws_size,
                              hipStream_t stream) {
    const float* x = (const float*)d_in[0];
    const float* w = (const float*)d_in[1];

    float* out0 = (float*)d_out;                       // quantized_st [N,D]
    float* out1 = out0 + (size_t)N_TOK * DIM;          // loss [N]
    float* out2 = out1 + N_TOK;                        // perplexity [1]
    float* out3 = out2 + 1;                            // indices [N] (as float)

    float* x2np   = (float*)d_ws;                      // 32768 f
    float* w2np   = x2np + N_TOK;                      // 4096 f
    int*   idx    = (int*)(w2np + K_CODES);            // 32768 i
    int*   counts = idx + N_TOK;                       // 4096 i
    int*   cand   = counts + K_CODES;                  // 32768*6 i

    hipMemsetAsync(counts, 0, K_CODES * sizeof(int), stream);

    rowsq_np_kernel<<<N_TOK / 32, 256, 0, stream>>>(x, x2np, N_TOK);
    rowsq_np_kernel<<<K_CODES / 32, 256, 0, stream>>>(w, w2np, K_CODES);
    argmin_kernel<<<N_TOK / 128, 256, 0, stream>>>(x, w, w2np, cand);
    refine_kernel<<<N_TOK / 4, 256, 0, stream>>>(x, w, x2np, w2np, cand, idx);
    gather_kernel<<<N_TOK / 4, 256, 0, stream>>>(x, w, idx, out0, out1, out3, counts);
    perplex_kernel<<<1, 256, 0, stream>>>(counts, out2);
}

// Round 4
// 630.625 us; speedup vs baseline: 3.5933x; 3.5933x over previous
//
#include <hip/hip_runtime.h>
#include <math.h>

#define N_TOK 32768
#define K_CODES 4096
#define DIM 512
#define COMMIT 0.25f
#define NCAND 8
#define NSPLIT 8
#define SPLIT_CODES (K_CODES / NSPLIT)   // 512
#define NSUB (SPLIT_CODES / 128)         // 4

typedef short s16x8 __attribute__((ext_vector_type(8)));
typedef float f32x4 __attribute__((ext_vector_type(4)));
typedef unsigned int uint32;
typedef unsigned long long u64;
typedef unsigned short u16;

__device__ __forceinline__ u16 f2bf(float f) {
    uint32 b = __float_as_uint(f);
    return (u16)((b + 0x7FFFu + ((b >> 16) & 1u)) >> 16);
}

// ---------------------------------------------------------------------------
// fp32 -> bf16 (RNE) bulk convert. n4 = element count / 4.
// ---------------------------------------------------------------------------
__global__ __launch_bounds__(256) void tobf16_kernel(const float* __restrict__ src,
                                                     u16* __restrict__ dst, int n4) {
    int i = blockIdx.x * 256 + threadIdx.x;
    int stride = gridDim.x * 256;
    for (; i < n4; i += stride) {
        float4 v = ((const float4*)src)[i];
        ushort4 o;
        o.x = f2bf(v.x); o.y = f2bf(v.y); o.z = f2bf(v.z); o.w = f2bf(v.w);
        ((ushort4*)dst)[i] = o;
    }
}

// ---------------------------------------------------------------------------
// numpy-exact fp32 row sum of squares (pairwise algorithm), from R3 (verified).
// ---------------------------------------------------------------------------
__global__ __launch_bounds__(256) void rowsq_np_kernel(const float* __restrict__ a,
                                                       float* __restrict__ out,
                                                       int nrows) {
    #pragma clang fp contract(off)
    const int gw   = (blockIdx.x * 256 + threadIdx.x) >> 6;
    const int lane = threadIdx.x & 63;
    const int row  = gw * 8 + (lane >> 3);
    const int j    = lane & 7;
    if (row >= nrows) return;
    const float* p = a + (size_t)row * DIM;
    float blk[4];
    #pragma unroll
    for (int b = 0; b < 4; ++b) {
        const float* q = p + b * 128;
        float v = q[j];
        float r = v * v;
        for (int i = 8; i < 128; i += 8) { float u = q[i + j]; r += u * u; }
        float s1 = r  + __shfl_xor(r, 1);
        float s2 = s1 + __shfl_xor(s1, 2);
        float s3 = s2 + __shfl_xor(s2, 4);
        blk[b] = s3;
    }
    float res = (blk[0] + blk[1]) + (blk[2] + blk[3]);
    if (j == 0) out[row] = res;
}

// ---------------------------------------------------------------------------
// MFMA bf16 screening. Block: 128 tokens x (NSUB subtiles of 128 codes) within
// one code split. Wave-tile 32 tok x 128 codes (2x8 MFMA grid of 16x16x32).
// Per-(lane,token) running top-2 as packed u32 keys:
//   key = bits(score + 0.0625) & ~63 | (sub*8 + ct)   (monotone, idx tiebreak)
// End: per-token merge of 32 entries -> top-6 u64 (valbits<<32 | code) to global.
// ---------------------------------------------------------------------------
__global__ __launch_bounds__(256, 3) void screen_kernel(const u16* __restrict__ xb,
                                                        const u16* __restrict__ wb,
                                                        const float* __restrict__ w2f,
                                                        u64* __restrict__ candPart) {
    __shared__ u16 As[128 * 40];   // 128 token rows, 32 k, pad to 40 u16 (80B)
    __shared__ u16 Bs[128 * 40];   // 128 code rows
    __shared__ u64 MS[128 * 32];   // merge scratch

    const int tid   = threadIdx.x;
    const int wv    = tid >> 6;
    const int lane  = tid & 63;
    const int q     = lane >> 4;
    const int n15   = lane & 15;
    const int m0    = blockIdx.x * 128;
    const int split = blockIdx.y;
    const int sbase = split * SPLIT_CODES;

    const int srow = tid >> 1;         // staging row 0..127
    const int sseg = (tid & 1) * 16;   // k-offset (u16 units)

    uint32 r1[8], r2[8];
    #pragma unroll
    for (int i = 0; i < 8; ++i) { r1[i] = 0xFFFFFFFFu; r2[i] = 0xFFFFFFFFu; }

    for (int sub = 0; sub < NSUB; ++sub) {
        const int n0 = sbase + sub * 128;

        float w2b[8];
        #pragma unroll
        for (int c = 0; c < 8; ++c) w2b[c] = w2f[n0 + c * 16 + n15] + 0.0625f;

        f32x4 acc[2][8];
        #pragma unroll
        for (int a = 0; a < 2; ++a)
            #pragma unroll
            for (int c = 0; c < 8; ++c) acc[a][c] = (f32x4){0.f, 0.f, 0.f, 0.f};

        for (int ch = 0; ch < 16; ++ch) {
            const int k0 = ch * 32;
            __syncthreads();
            {
                const u16* sa = xb + (size_t)(m0 + srow) * DIM + k0 + sseg;
                uint4 v0 = *(const uint4*)(sa);
                uint4 v1 = *(const uint4*)(sa + 8);
                *(uint4*)&As[srow * 40 + sseg]     = v0;
                *(uint4*)&As[srow * 40 + sseg + 8] = v1;
                const u16* sb = wb + (size_t)(n0 + srow) * DIM + k0 + sseg;
                uint4 u0 = *(const uint4*)(sb);
                uint4 u1 = *(const uint4*)(sb + 8);
                *(uint4*)&Bs[srow * 40 + sseg]     = u0;
                *(uint4*)&Bs[srow * 40 + sseg + 8] = u1;
            }
            __syncthreads();
            s16x8 af[2], bf[8];
            #pragma unroll
            for (int a = 0; a < 2; ++a)
                af[a] = *(const s16x8*)&As[(wv * 32 + a * 16 + n15) * 40 + q * 8];
            #pragma unroll
            for (int c = 0; c < 8; ++c)
                bf[c] = *(const s16x8*)&Bs[(c * 16 + n15) * 40 + q * 8];
            #pragma unroll
            for (int a = 0; a < 2; ++a)
                #pragma unroll
                for (int c = 0; c < 8; ++c)
                    acc[a][c] = __builtin_amdgcn_mfma_f32_16x16x32_bf16(af[a], bf[c], acc[a][c], 0, 0, 0);
        }

        // fold: token = wv*32 + a*16 + q*4 + r ; code = n0 + c*16 + n15
        #pragma unroll
        for (int a = 0; a < 2; ++a)
            #pragma unroll
            for (int r = 0; r < 4; ++r) {
                const int ti = a * 4 + r;
                #pragma unroll
                for (int c = 0; c < 8; ++c) {
                    float s = fmaf(-2.0f, acc[a][c][r], w2b[c]);
                    uint32 key = (__float_as_uint(s) & 0xFFFFFFC0u) | (uint32)(sub * 8 + c);
                    uint32 mx = r1[ti] > key ? r1[ti] : key;
                    r1[ti] = r1[ti] < key ? r1[ti] : key;
                    r2[ti] = r2[ti] < mx ? r2[ti] : mx;
                }
            }
    }

    __syncthreads();
    #pragma unroll
    for (int ti = 0; ti < 8; ++ti) {
        const int a = ti >> 2, r = ti & 3;
        const int token = wv * 32 + a * 16 + q * 4 + r;
        #pragma unroll
        for (int e = 0; e < 2; ++e) {
            uint32 k  = e ? r2[ti] : r1[ti];
            uint32 vb = k & 0xFFFFFFC0u;
            uint32 id = k & 63u;
            uint32 code = (uint32)(sbase + (id >> 3) * 128 + (id & 7) * 16 + n15);
            MS[token * 32 + n15 * 2 + e] = ((u64)vb << 32) | code;
        }
    }
    __syncthreads();
    if (tid < 128) {
        u64 best[6];
        #pragma unroll
        for (int c = 0; c < 6; ++c) best[c] = 0xFFFFFFFFFFFFFFFFull;
        for (int sNdx = 0; sNdx < 32; ++sNdx) {
            u64 v = MS[tid * 32 + sNdx];
            if (v < best[5]) {
                best[5] = v;
                #pragma unroll
                for (int p = 5; p > 0; --p)
                    if (best[p] < best[p - 1]) { u64 tv = best[p]; best[p] = best[p - 1]; best[p - 1] = tv; }
            }
        }
        u64* dst = candPart + ((size_t)split * N_TOK + (m0 + tid)) * 6;
        #pragma unroll
        for (int c = 0; c < 6; ++c) dst[c] = best[c];
    }
}

// ---------------------------------------------------------------------------
// Merge per-split top-6 lists -> global top-NCAND candidate codes per token.
// ---------------------------------------------------------------------------
__global__ __launch_bounds__(256) void mergecand_kernel(const u64* __restrict__ candPart,
                                                        int* __restrict__ candF) {
    int t = blockIdx.x * 256 + threadIdx.x;
    u64 best[NCAND];
    #pragma unroll
    for (int c = 0; c < NCAND; ++c) best[c] = 0xFFFFFFFFFFFFFFFFull;
    for (int s = 0; s < NSPLIT; ++s) {
        const u64* src = candPart + ((size_t)s * N_TOK + t) * 6;
        #pragma unroll
        for (int c = 0; c < 6; ++c) {
            u64 v = src[c];
            if (v < best[NCAND - 1]) {
                best[NCAND - 1] = v;
                #pragma unroll
                for (int p = NCAND - 1; p > 0; --p)
                    if (best[p] < best[p - 1]) { u64 tv = best[p]; best[p] = best[p - 1]; best[p - 1] = tv; }
            }
        }
    }
    #pragma unroll
    for (int c = 0; c < NCAND; ++c) candF[(size_t)t * NCAND + c] = (int)(best[c] & 0xFFFu);
}

// ---------------------------------------------------------------------------
// np-exact refine over NCAND candidates (R3-verified arithmetic).
// d_k = fl32( fl32(x2_i + w2_k) - 2f * fl32(dot_fp64) ); argmin, ties->lowest k.
// ---------------------------------------------------------------------------
__global__ __launch_bounds__(256) void refine_kernel(const float* __restrict__ x,
                                                     const float* __restrict__ w,
                                                     const float* __restrict__ x2np,
                                                     const float* __restrict__ w2np,
                                                     const int* __restrict__ cand,
                                                     int* __restrict__ idx) {
    const int t    = blockIdx.x * 4 + (threadIdx.x >> 6);
    const int lane = threadIdx.x & 63;

    const float* xr = x + (size_t)t * DIM;
    float xv[8];
    #pragma unroll
    for (int j = 0; j < 8; ++j) xv[j] = xr[lane + 64 * j];
    const float x2 = x2np[t];

    float bd = 3.4e38f;
    int   bk = 0x7fffffff;
    for (int c = 0; c < NCAND; ++c) {
        int k = cand[(size_t)t * NCAND + c];
        const float* wr = w + (size_t)k * DIM;
        double m = 0.0;
        #pragma unroll
        for (int j = 0; j < 8; ++j)
            m = fma((double)xv[j], (double)wr[lane + 64 * j], m);
        #pragma unroll
        for (int off = 32; off >= 1; off >>= 1) m += __shfl_down(m, off);
        if (lane == 0) {
            #pragma clang fp contract(off)
            float m32 = (float)m;
            float T1  = x2 + w2np[k];
            float d   = T1 - 2.0f * m32;
            if (d < bd || (d == bd && k < bk)) { bd = d; bk = k; }
        }
    }
    if (lane == 0) idx[t] = bk;
}

// ---------------------------------------------------------------------------
// gather + straight-through output + loss + counts (R3-verified).
// ---------------------------------------------------------------------------
__global__ __launch_bounds__(256) void gather_kernel(const float* __restrict__ x,
                                                     const float* __restrict__ w,
                                                     const int* __restrict__ idx,
                                                     float* __restrict__ out_q,
                                                     float* __restrict__ out_loss,
                                                     float* __restrict__ out_ind,
                                                     int* __restrict__ counts) {
    const int wave = threadIdx.x >> 6;
    const int lane = threadIdx.x & 63;
    const int token = blockIdx.x * 4 + wave;
    const int k = idx[token];

    const float4* xr = (const float4*)(x + (size_t)token * DIM);
    const float4* wr = (const float4*)(w + (size_t)k * DIM);
    float4*       qo = (float4*)(out_q + (size_t)token * DIM);

    float ss = 0.f;
    #pragma unroll
    for (int j = 0; j < 2; ++j) {
        int e = lane + j * 64;
        float4 xv = xr[e];
        float4 wv = wr[e];
        float4 d, o;
        d.x = wv.x - xv.x; o.x = xv.x + d.x;
        d.y = wv.y - xv.y; o.y = xv.y + d.y;
        d.z = wv.z - xv.z; o.z = xv.z + d.z;
        d.w = wv.w - xv.w; o.w = xv.w + d.w;
        ss += d.x * d.x + d.y * d.y + d.z * d.z + d.w * d.w;
        qo[e] = o;
    }
    #pragma unroll
    for (int off = 32; off >= 1; off >>= 1) ss += __shfl_down(ss, off);
    if (lane == 0) {
        float lm = ss * (1.0f / DIM);
        out_loss[token] = lm + COMMIT * lm;
        out_ind[token] = (float)k;
        atomicAdd(&counts[k], 1);
    }
}

// ---------------------------------------------------------------------------
// perplexity (R3-verified).
// ---------------------------------------------------------------------------
__global__ __launch_bounds__(256) void perplex_kernel(const int* __restrict__ counts,
                                                      float* __restrict__ out2) {
    __shared__ double red[4];
    const int tid = threadIdx.x;
    const int lane = tid & 63;
    const int wid = tid >> 6;
    double s = 0.0;
    for (int t = tid; t < K_CODES; t += 256) {
        int c = counts[t];
        if (c) {
            double p = (double)c * (1.0 / N_TOK);
            s += p * log(p + 1e-10);
        }
    }
    #pragma unroll
    for (int off = 32; off >= 1; off >>= 1) s += __shfl_down(s, off);
    if (lane == 0) red[wid] = s;
    __syncthreads();
    if (tid == 0) {
        double t = red[0] + red[1] + red[2] + red[3];
        out2[0] = (float)exp(-t);
    }
}

// ---------------------------------------------------------------------------
extern "C" void kernel_launch(void* const* d_in, const int* in_sizes, int n_in,
                              void* d_out, int out_size, void* d_ws, size_t ws_size,
                              hipStream_t stream) {
    const float* x = (const float*)d_in[0];
    const float* w = (const float*)d_in[1];

    float* out0 = (float*)d_out;                       // quantized_st [N,D]
    float* out1 = out0 + (size_t)N_TOK * DIM;          // loss [N]
    float* out2 = out1 + N_TOK;                        // perplexity [1]
    float* out3 = out2 + 1;                            // indices [N] (as float)

    // workspace layout (8B-aligned chunks first)
    u64*   candPart = (u64*)d_ws;                                 // NSPLIT*N_TOK*6
    float* x2np     = (float*)(candPart + (size_t)NSPLIT * N_TOK * 6);
    float* w2np     = x2np + N_TOK;
    int*   idx      = (int*)(w2np + K_CODES);
    int*   counts   = idx + N_TOK;
    int*   candF    = counts + K_CODES;                           // N_TOK*NCAND
    u16*   x_bf     = (u16*)(candF + (size_t)N_TOK * NCAND);      // N_TOK*DIM
    u16*   w_bf     = x_bf + (size_t)N_TOK * DIM;                 // K_CODES*DIM

    hipMemsetAsync(counts, 0, K_CODES * sizeof(int), stream);

    tobf16_kernel<<<4096, 256, 0, stream>>>(x, x_bf, N_TOK * DIM / 4);
    tobf16_kernel<<<2048, 256, 0, stream>>>(w, w_bf, K_CODES * DIM / 4);
    rowsq_np_kernel<<<N_TOK / 32, 256, 0, stream>>>(x, x2np, N_TOK);
    rowsq_np_kernel<<<K_CODES / 32, 256, 0, stream>>>(w, w2np, K_CODES);
    screen_kernel<<<dim3(N_TOK / 128, NSPLIT), 256, 0, stream>>>(x_bf, w_bf, w2np, candPart);
    mergecand_kernel<<<N_TOK / 256, 256, 0, stream>>>(candPart, candF);
    refine_kernel<<<N_TOK / 4, 256, 0, stream>>>(x, w, x2np, w2np, candF, idx);
    gather_kernel<<<N_TOK / 4, 256, 0, stream>>>(x, w, idx, out0, out1, out3, counts);
    perplex_kernel<<<1, 256, 0, stream>>>(counts, out2);
}

// Round 5
// 481.401 us; speedup vs baseline: 4.7072x; 1.3100x over previous
//
#include <hip/hip_runtime.h>
#include <math.h>

#define N_TOK 32768
#define K_CODES 4096
#define DIM 512
#define COMMIT 0.25f
#define NCAND 8
#define NSPLIT 2
#define SPLIT_CODES (K_CODES / NSPLIT)   // 2048
#define NITER (SPLIT_CODES / 256)        // 8 col-iterations of 256 codes
#define BIAS 0.125f

typedef short s16x8 __attribute__((ext_vector_type(8)));
typedef float f32x4 __attribute__((ext_vector_type(4)));
typedef unsigned int uint32;
typedef unsigned long long u64;
typedef unsigned short u16;

__device__ __forceinline__ u16 f2bf(float f) {
    uint32 b = __float_as_uint(f);
    return (u16)((b + 0x7FFFu + ((b >> 16) & 1u)) >> 16);
}

// ---------------------------------------------------------------------------
// fp32 -> bf16 (RNE) bulk convert.
// ---------------------------------------------------------------------------
__global__ __launch_bounds__(256) void tobf16_kernel(const float* __restrict__ src,
                                                     u16* __restrict__ dst, int n4) {
    int i = blockIdx.x * 256 + threadIdx.x;
    int stride = gridDim.x * 256;
    for (; i < n4; i += stride) {
        float4 v = ((const float4*)src)[i];
        ushort4 o;
        o.x = f2bf(v.x); o.y = f2bf(v.y); o.z = f2bf(v.z); o.w = f2bf(v.w);
        ((ushort4*)dst)[i] = o;
    }
}

// ---------------------------------------------------------------------------
// numpy-exact fp32 row sum of squares (pairwise algorithm) — R3-verified.
// ---------------------------------------------------------------------------
__global__ __launch_bounds__(256) void rowsq_np_kernel(const float* __restrict__ a,
                                                       float* __restrict__ out,
                                                       int nrows) {
    #pragma clang fp contract(off)
    const int gw   = (blockIdx.x * 256 + threadIdx.x) >> 6;
    const int lane = threadIdx.x & 63;
    const int row  = gw * 8 + (lane >> 3);
    const int j    = lane & 7;
    if (row >= nrows) return;
    const float* p = a + (size_t)row * DIM;
    float blk[4];
    #pragma unroll
    for (int b = 0; b < 4; ++b) {
        const float* q = p + b * 128;
        float v = q[j];
        float r = v * v;
        for (int i = 8; i < 128; i += 8) { float u = q[i + j]; r += u * u; }
        float s1 = r  + __shfl_xor(r, 1);
        float s2 = s1 + __shfl_xor(s1, 2);
        float s3 = s2 + __shfl_xor(s2, 4);
        blk[b] = s3;
    }
    float res = (blk[0] + blk[1]) + (blk[2] + blk[3]);
    if (j == 0) out[row] = res;
}

// ---------------------------------------------------------------------------
// MFMA bf16 screen. Block: 512 thr = 8 waves, tile 128 tok x 256 codes/iter.
// Wave tile 64 tok x 64 codes (4x4 grid of 16x16x32 MFMA). K staged BK=64,
// double-buffered LDS, XOR-swizzled 128B rows (16B quantum q -> q^(row&7)).
// Per-(lane,token) top-2 packed keys; final full merge in LDS -> top-6/split.
// ---------------------------------------------------------------------------
__global__ __launch_bounds__(512, 2) void screen_kernel(const u16* __restrict__ xb,
                                                        const u16* __restrict__ wb,
                                                        const float* __restrict__ w2f,
                                                        u64* __restrict__ candPart) {
    __shared__ __attribute__((aligned(16))) u16 POOL[49152];  // 96 KiB
    // Xs buffers: 128 rows x 64 elems (128 B rows): [0]=0, [1]=8192 (u16 units)
    // Ws buffers: 256 rows x 64 elems: [0]=16384, [1]=32768

    const int tid  = threadIdx.x;
    const int wv   = tid >> 6;
    const int wt   = wv >> 2;          // token half (0/1)
    const int wc   = wv & 3;           // code column (0..3)
    const int lane = tid & 63;
    const int quad = lane >> 4;
    const int n15  = lane & 15;
    const int m0   = blockIdx.x * 128;
    const int sbase = blockIdx.y * SPLIT_CODES;

    // staging roles
    const int xr = tid >> 2, xq = (tid & 3) * 2;   // X: 128 rows, 2 quanta each
    const int wr_ = tid >> 1, wq = (tid & 1) * 4;  // W: 256 rows, 4 quanta each
    const u16* xsrc = xb + (size_t)(m0 + xr) * DIM + xq * 8;

    uint32 r1[16], r2[16];
    #pragma unroll
    for (int i = 0; i < 16; ++i) { r1[i] = 0xFFFFFFFFu; r2[i] = 0xFFFFFFFFu; }

    for (int it = 0; it < NITER; ++it) {
        const int nbase = sbase + it * 256;
        const u16* wsrc = wb + (size_t)(nbase + wr_) * DIM + wq * 8;

        float w2pb[4];
        #pragma unroll
        for (int c = 0; c < 4; ++c) w2pb[c] = w2f[nbase + wc * 64 + c * 16 + n15] + BIAS;

        f32x4 acc[4][4];
        #pragma unroll
        for (int i = 0; i < 4; ++i)
            #pragma unroll
            for (int c = 0; c < 4; ++c) acc[i][c] = (f32x4){0.f, 0.f, 0.f, 0.f};

        // stage chunk 0 into buffer 0
        uint4 xv[2], wv4[4];
        #pragma unroll
        for (int j = 0; j < 2; ++j) xv[j]  = *(const uint4*)(xsrc + j * 8);
        #pragma unroll
        for (int j = 0; j < 4; ++j) wv4[j] = *(const uint4*)(wsrc + j * 8);
        #pragma unroll
        for (int j = 0; j < 2; ++j)
            *(uint4*)&POOL[xr * 64 + ((xq + j) ^ (xr & 7)) * 8] = xv[j];
        #pragma unroll
        for (int j = 0; j < 4; ++j)
            *(uint4*)&POOL[16384 + wr_ * 64 + ((wq + j) ^ (wr_ & 7)) * 8] = wv4[j];
        __syncthreads();

        for (int kc = 0; kc < 8; ++kc) {
            if (kc < 7) {   // prefetch next chunk to regs (overlaps MFMA below)
                #pragma unroll
                for (int j = 0; j < 2; ++j) xv[j]  = *(const uint4*)(xsrc + (kc + 1) * 64 + j * 8);
                #pragma unroll
                for (int j = 0; j < 4; ++j) wv4[j] = *(const uint4*)(wsrc + (kc + 1) * 64 + j * 8);
            }
            const u16* X = &POOL[(kc & 1) * 8192];
            const u16* W = &POOL[16384 + (kc & 1) * 16384];
            #pragma unroll
            for (int s = 0; s < 2; ++s) {
                const int lq = s * 4 + quad;
                s16x8 af[4], bf[4];
                #pragma unroll
                for (int i = 0; i < 4; ++i) {
                    const int tr = wt * 64 + i * 16 + n15;
                    af[i] = *(const s16x8*)&X[tr * 64 + (lq ^ (tr & 7)) * 8];
                }
                #pragma unroll
                for (int c = 0; c < 4; ++c) {
                    const int cr = wc * 64 + c * 16 + n15;
                    bf[c] = *(const s16x8*)&W[cr * 64 + (lq ^ (cr & 7)) * 8];
                }
                #pragma unroll
                for (int i = 0; i < 4; ++i)
                    #pragma unroll
                    for (int c = 0; c < 4; ++c)
                        acc[i][c] = __builtin_amdgcn_mfma_f32_16x16x32_bf16(af[i], bf[c], acc[i][c], 0, 0, 0);
            }
            if (kc < 7) {
                const int nb = (kc + 1) & 1;
                #pragma unroll
                for (int j = 0; j < 2; ++j)
                    *(uint4*)&POOL[nb * 8192 + xr * 64 + ((xq + j) ^ (xr & 7)) * 8] = xv[j];
                #pragma unroll
                for (int j = 0; j < 4; ++j)
                    *(uint4*)&POOL[16384 + nb * 16384 + wr_ * 64 + ((wq + j) ^ (wr_ & 7)) * 8] = wv4[j];
            }
            __syncthreads();
        }

        // fold this 256-code column into running top-2 per (lane, token-slot)
        #pragma unroll
        for (int i = 0; i < 4; ++i)
            #pragma unroll
            for (int r = 0; r < 4; ++r) {
                const int ti = i * 4 + r;
                #pragma unroll
                for (int c = 0; c < 4; ++c) {
                    float s = fmaf(-2.0f, acc[i][c][r], w2pb[c]);
                    uint32 key = (__float_as_uint(s) & 0xFFFFFFC0u) | (uint32)((it << 2) | c);
                    uint32 mx = r1[ti] > key ? r1[ti] : key;
                    r1[ti] = r1[ti] < key ? r1[ti] : key;
                    r2[ti] = r2[ti] < mx ? r2[ti] : mx;
                }
            }
    }

    // ------- merge: all 128 entries per token via LDS, two phases by wt -----
    u64* MS = (u64*)POOL;   // 64 tokens x 128 entries = 64 KiB
    for (int phase = 0; phase < 2; ++phase) {
        __syncthreads();
        if (wt == phase) {
            #pragma unroll
            for (int ti = 0; ti < 16; ++ti) {
                const int i = ti >> 2, r = ti & 3;
                const int tloc = i * 16 + quad * 4 + r;     // 0..63
                #pragma unroll
                for (int e = 0; e < 2; ++e) {
                    uint32 k  = e ? r2[ti] : r1[ti];
                    uint32 vb = k & 0xFFFFFFC0u;
                    uint32 id = k & 63u;
                    uint32 code = (uint32)(sbase + (id >> 2) * 256 + wc * 64 + (id & 3) * 16 + n15);
                    MS[tloc * 128 + (wc * 16 + n15) * 2 + e] = ((u64)vb << 32) | code;
                }
            }
        }
        __syncthreads();
        if (tid < 64) {
            u64 best[6];
            #pragma unroll
            for (int c = 0; c < 6; ++c) best[c] = 0xFFFFFFFFFFFFFFFFull;
            for (int e = 0; e < 128; ++e) {
                u64 v = MS[tid * 128 + e];
                if (v < best[5]) {
                    best[5] = v;
                    #pragma unroll
                    for (int p = 5; p > 0; --p)
                        if (best[p] < best[p - 1]) { u64 tv = best[p]; best[p] = best[p - 1]; best[p - 1] = tv; }
                }
            }
            const int token = m0 + phase * 64 + tid;
            u64* dst = candPart + ((size_t)blockIdx.y * N_TOK + token) * 6;
            #pragma unroll
            for (int c = 0; c < 6; ++c) dst[c] = best[c];
        }
    }
}

// ---------------------------------------------------------------------------
// Merge per-split top-6 lists -> global top-NCAND candidate codes per token.
// ---------------------------------------------------------------------------
__global__ __launch_bounds__(256) void mergecand_kernel(const u64* __restrict__ candPart,
                                                        int* __restrict__ candF) {
    int t = blockIdx.x * 256 + threadIdx.x;
    u64 best[NCAND];
    #pragma unroll
    for (int c = 0; c < NCAND; ++c) best[c] = 0xFFFFFFFFFFFFFFFFull;
    for (int s = 0; s < NSPLIT; ++s) {
        const u64* src = candPart + ((size_t)s * N_TOK + t) * 6;
        #pragma unroll
        for (int c = 0; c < 6; ++c) {
            u64 v = src[c];
            if (v < best[NCAND - 1]) {
                best[NCAND - 1] = v;
                #pragma unroll
                for (int p = NCAND - 1; p > 0; --p)
                    if (best[p] < best[p - 1]) { u64 tv = best[p]; best[p] = best[p - 1]; best[p - 1] = tv; }
            }
        }
    }
    #pragma unroll
    for (int c = 0; c < NCAND; ++c) candF[(size_t)t * NCAND + c] = (int)(best[c] & 0xFFFu);
}

// ---------------------------------------------------------------------------
// np-exact refine over NCAND candidates (R3-verified arithmetic).
// ---------------------------------------------------------------------------
__global__ __launch_bounds__(256) void refine_kernel(const float* __restrict__ x,
                                                     const float* __restrict__ w,
                                                     const float* __restrict__ x2np,
                                                     const float* __restrict__ w2np,
                                                     const int* __restrict__ cand,
                                                     int* __restrict__ idx) {
    const int t    = blockIdx.x * 4 + (threadIdx.x >> 6);
    const int lane = threadIdx.x & 63;

    const float* xr = x + (size_t)t * DIM;
    float xv[8];
    #pragma unroll
    for (int j = 0; j < 8; ++j) xv[j] = xr[lane + 64 * j];
    const float x2 = x2np[t];

    float bd = 3.4e38f;
    int   bk = 0x7fffffff;
    for (int c = 0; c < NCAND; ++c) {
        int k = cand[(size_t)t * NCAND + c];
        const float* wr = w + (size_t)k * DIM;
        double m = 0.0;
        #pragma unroll
        for (int j = 0; j < 8; ++j)
            m = fma((double)xv[j], (double)wr[lane + 64 * j], m);
        #pragma unroll
        for (int off = 32; off >= 1; off >>= 1) m += __shfl_down(m, off);
        if (lane == 0) {
            #pragma clang fp contract(off)
            float m32 = (float)m;
            float T1  = x2 + w2np[k];
            float d   = T1 - 2.0f * m32;
            if (d < bd || (d == bd && k < bk)) { bd = d; bk = k; }
        }
    }
    if (lane == 0) idx[t] = bk;
}

// ---------------------------------------------------------------------------
// gather + straight-through output + loss + counts (R3-verified).
// ---------------------------------------------------------------------------
__global__ __launch_bounds__(256) void gather_kernel(const float* __restrict__ x,
                                                     const float* __restrict__ w,
                                                     const int* __restrict__ idx,
                                                     float* __restrict__ out_q,
                                                     float* __restrict__ out_loss,
                                                     float* __restrict__ out_ind,
                                                     int* __restrict__ counts) {
    const int wave = threadIdx.x >> 6;
    const int lane = threadIdx.x & 63;
    const int token = blockIdx.x * 4 + wave;
    const int k = idx[token];

    const float4* xr = (const float4*)(x + (size_t)token * DIM);
    const float4* wr = (const float4*)(w + (size_t)k * DIM);
    float4*       qo = (float4*)(out_q + (size_t)token * DIM);

    float ss = 0.f;
    #pragma unroll
    for (int j = 0; j < 2; ++j) {
        int e = lane + j * 64;
        float4 xv = xr[e];
        float4 wv = wr[e];
        float4 d, o;
        d.x = wv.x - xv.x; o.x = xv.x + d.x;
        d.y = wv.y - xv.y; o.y = xv.y + d.y;
        d.z = wv.z - xv.z; o.z = xv.z + d.z;
        d.w = wv.w - xv.w; o.w = xv.w + d.w;
        ss += d.x * d.x + d.y * d.y + d.z * d.z + d.w * d.w;
        qo[e] = o;
    }
    #pragma unroll
    for (int off = 32; off >= 1; off >>= 1) ss += __shfl_down(ss, off);
    if (lane == 0) {
        float lm = ss * (1.0f / DIM);
        out_loss[token] = lm + COMMIT * lm;
        out_ind[token] = (float)k;
        atomicAdd(&counts[k], 1);
    }
}

// ---------------------------------------------------------------------------
// perplexity (R3-verified).
// ---------------------------------------------------------------------------
__global__ __launch_bounds__(256) void perplex_kernel(const int* __restrict__ counts,
                                                      float* __restrict__ out2) {
    __shared__ double red[4];
    const int tid = threadIdx.x;
    const int lane = tid & 63;
    const int wid = tid >> 6;
    double s = 0.0;
    for (int t = tid; t < K_CODES; t += 256) {
        int c = counts[t];
        if (c) {
            double p = (double)c * (1.0 / N_TOK);
            s += p * log(p + 1e-10);
        }
    }
    #pragma unroll
    for (int off = 32; off >= 1; off >>= 1) s += __shfl_down(s, off);
    if (lane == 0) red[wid] = s;
    __syncthreads();
    if (tid == 0) {
        double t = red[0] + red[1] + red[2] + red[3];
        out2[0] = (float)exp(-t);
    }
}

// ---------------------------------------------------------------------------
extern "C" void kernel_launch(void* const* d_in, const int* in_sizes, int n_in,
                              void* d_out, int out_size, void* d_ws, size_t ws_size,
                              hipStream_t stream) {
    const float* x = (const float*)d_in[0];
    const float* w = (const float*)d_in[1];

    float* out0 = (float*)d_out;                       // quantized_st [N,D]
    float* out1 = out0 + (size_t)N_TOK * DIM;          // loss [N]
    float* out2 = out1 + N_TOK;                        // perplexity [1]
    float* out3 = out2 + 1;                            // indices [N] (as float)

    // workspace layout (8B-aligned chunks first)
    u64*   candPart = (u64*)d_ws;                                 // NSPLIT*N_TOK*6
    float* x2np     = (float*)(candPart + (size_t)NSPLIT * N_TOK * 6);
    float* w2np     = x2np + N_TOK;
    int*   idx      = (int*)(w2np + K_CODES);
    int*   counts   = idx + N_TOK;
    int*   candF    = counts + K_CODES;                           // N_TOK*NCAND
    u16*   x_bf     = (u16*)(candF + (size_t)N_TOK * NCAND);      // N_TOK*DIM
    u16*   w_bf     = x_bf + (size_t)N_TOK * DIM;                 // K_CODES*DIM

    hipMemsetAsync(counts, 0, K_CODES * sizeof(int), stream);

    tobf16_kernel<<<4096, 256, 0, stream>>>(x, x_bf, N_TOK * DIM / 4);
    tobf16_kernel<<<2048, 256, 0, stream>>>(w, w_bf, K_CODES * DIM / 4);
    rowsq_np_kernel<<<N_TOK / 32, 256, 0, stream>>>(x, x2np, N_TOK);
    rowsq_np_kernel<<<K_CODES / 32, 256, 0, stream>>>(w, w2np, K_CODES);
    screen_kernel<<<dim3(N_TOK / 128, NSPLIT), 512, 0, stream>>>(x_bf, w_bf, w2np, candPart);
    mergecand_kernel<<<N_TOK / 256, 256, 0, stream>>>(candPart, candF);
    refine_kernel<<<N_TOK / 4, 256, 0, stream>>>(x, w, x2np, w2np, candF, idx);
    gather_kernel<<<N_TOK / 4, 256, 0, stream>>>(x, w, idx, out0, out1, out3, counts);
    perplex_kernel<<<1, 256, 0, stream>>>(counts, out2);
}